// Round 1
// baseline (3972.437 us; speedup 1.0000x reference)
//
#include <hip/hip_runtime.h>

#define BB 32
#define CC 128
#define HH 12
#define WW 1200
#define DIN 1536
#define FIXD 768
#define OVL 4
#define GG 6
#define DD 512
#define KK 1024
#define TT 300
#define NV 9600        /* B*T vectors per group */
#define MROWS 38400    /* B*W */

// workspace layout (float offsets)
#define Y_OFF     0
#define ET_OFF    29491200
#define NORM_OFF  32636928
#define IDX_OFF   32643072
#define LOSS_OFF  32700672

// ---------------- K1: fused gather + proj_down GEMM ----------------
// Y[n][f] = sum_k z_perm[n][k] * w_down[f][k];  n=(b,w), k=(c,h)
__global__ __launch_bounds__(256) void k_gemm_down(const float* __restrict__ z,
                                                   const float* __restrict__ w_down,
                                                   float* __restrict__ Y) {
    __shared__ float As[16][68];
    __shared__ float Bs[16][68];
    const int bm = blockIdx.x, bn = blockIdx.y;
    const int tid = threadIdx.x;
    const int rbase = (tid >> 4) << 2;
    const int cbase = (tid & 15) << 2;
    const int n0 = bm * 64, f0 = bn * 64;
    float acc[4][4] = {};
    for (int kt = 0; kt < DIN; kt += 16) {
        #pragma unroll
        for (int i = 0; i < 4; i++) {
            int flat = tid + i * 256;
            int row = flat & 63, kk = flat >> 6;
            int n = n0 + row;
            int k = kt + kk;
            int b = n / WW, w = n - b * WW;
            int c = k / HH, h = k - c * HH;
            As[kk][row] = z[((b * CC + c) * HH + h) * WW + w];
        }
        {
            int col = tid >> 2, q = tid & 3;
            const float4 v = *(const float4*)&w_down[(f0 + col) * DIN + kt + q * 4];
            Bs[q * 4 + 0][col] = v.x;
            Bs[q * 4 + 1][col] = v.y;
            Bs[q * 4 + 2][col] = v.z;
            Bs[q * 4 + 3][col] = v.w;
        }
        __syncthreads();
        #pragma unroll
        for (int k = 0; k < 16; k++) {
            const float4 a = *(const float4*)&As[k][rbase];
            const float4 b = *(const float4*)&Bs[k][cbase];
            const float av[4] = {a.x, a.y, a.z, a.w};
            const float bv[4] = {b.x, b.y, b.z, b.w};
            #pragma unroll
            for (int i = 0; i < 4; i++)
                #pragma unroll
                for (int j = 0; j < 4; j++)
                    acc[i][j] = fmaf(av[i], bv[j], acc[i][j]);
        }
        __syncthreads();
    }
    #pragma unroll
    for (int i = 0; i < 4; i++) {
        float4 o;
        o.x = acc[i][0]; o.y = acc[i][1]; o.z = acc[i][2]; o.w = acc[i][3];
        *(float4*)&Y[(n0 + rbase + i) * FIXD + f0 + cbase] = o;
    }
}

// ---------------- K2: transpose codebook emb(g,d,k) -> ET(g,k,d) ----------------
__global__ __launch_bounds__(256) void k_transpose(const float* __restrict__ emb,
                                                   float* __restrict__ ET) {
    int i = blockIdx.x * 256 + threadIdx.x;
    if (i >= GG * KK * DD) return;
    int d = i & 511;
    int rem = i >> 9;          // g*K + k
    int k = rem & 1023;
    int g = rem >> 10;
    ET[i] = emb[((g * DD + d) << 10) + k];
}

// ---------------- K2b: per-code squared norms (fp64 accumulate) ----------------
__global__ __launch_bounds__(64) void k_norms(const float* __restrict__ ET,
                                              float* __restrict__ norms) {
    const int code = blockIdx.x;   // g*K + k, 6144 total
    const int lane = threadIdx.x;
    const float* row = ET + code * DD;
    double s = 0.0;
    #pragma unroll
    for (int r = 0; r < 8; r++) {
        float v = row[lane + r * 64];
        s += (double)v * (double)v;
    }
    #pragma unroll
    for (int off = 32; off; off >>= 1) s += __shfl_down(s, off);
    if (lane == 0) norms[code] = (float)s;
}

// ---------------- K3: distances + argmin ----------------
// 16 vectors per block, all 1024 codes. score = |e|^2 - 2 z.e  (|z|^2 cancels)
__global__ __launch_bounds__(256) void k_dist(const float* __restrict__ Y,
                                              const float* __restrict__ ET,
                                              const float* __restrict__ norms,
                                              int* __restrict__ idx_out) {
    __shared__ float Zt[512][20];   // [d][m], padded
    __shared__ float Es[8][516];    // [k-sub][code], padded; reused for reduction
    const int g = blockIdx.y;
    const int bm = blockIdx.x;
    const int tid = threadIdx.x;

    // stage 16 vectors (transposed) into LDS
    #pragma unroll
    for (int i = 0; i < 32; i++) {
        int flat = tid + i * 256;       // 0..8191
        int m = flat >> 9, d = flat & 511;
        int v = bm * 16 + m;
        int b = v / TT, t = v - b * TT;
        int p = g * DD + d;
        int s = p / FIXD, f = p - s * FIXD;
        Zt[d][m] = Y[(b * WW + t * OVL + s) * FIXD + f];
    }

    const int vq = tid & 3;        // 4 vectors each
    const int cq = tid >> 2;       // 0..63, 8 codes each per chunk
    float best[4];
    int bidx[4];
    #pragma unroll
    for (int i = 0; i < 4; i++) { best[i] = 3.4e38f; bidx[i] = 0; }

    const float* ETg = ET + g * KK * DD;

    for (int chunk = 0; chunk < 2; chunk++) {
        float acc[4][8];
        #pragma unroll
        for (int i = 0; i < 4; i++)
            #pragma unroll
            for (int j = 0; j < 8; j++) acc[i][j] = 0.0f;

        for (int kt = 0; kt < 64; kt++) {
            __syncthreads();
            // stage 512 codes x 8 d's
            #pragma unroll
            for (int i = 0; i < 4; i++) {
                int flat4 = tid + i * 256;     // 0..1023
                int code = flat4 >> 1, dq = flat4 & 1;
                const float4 v = *(const float4*)&ETg[(chunk * 512 + code) * DD + kt * 8 + dq * 4];
                Es[dq * 4 + 0][code] = v.x;
                Es[dq * 4 + 1][code] = v.y;
                Es[dq * 4 + 2][code] = v.z;
                Es[dq * 4 + 3][code] = v.w;
            }
            __syncthreads();
            #pragma unroll
            for (int k = 0; k < 8; k++) {
                const float4 z4 = *(const float4*)&Zt[kt * 8 + k][vq * 4];
                const float4 ea = *(const float4*)&Es[k][cq * 8];
                const float4 eb = *(const float4*)&Es[k][cq * 8 + 4];
                const float zv[4] = {z4.x, z4.y, z4.z, z4.w};
                const float ev[8] = {ea.x, ea.y, ea.z, ea.w, eb.x, eb.y, eb.z, eb.w};
                #pragma unroll
                for (int i = 0; i < 4; i++)
                    #pragma unroll
                    for (int j = 0; j < 8; j++)
                        acc[i][j] = fmaf(zv[i], ev[j], acc[i][j]);
            }
        }
        // fold in norms, update running argmin (ascending code order -> first-index ties)
        #pragma unroll
        for (int j = 0; j < 8; j++) {
            int c = chunk * 512 + cq * 8 + j;
            float nrm = norms[g * KK + c];
            #pragma unroll
            for (int i = 0; i < 4; i++) {
                float score = nrm - 2.0f * acc[i][j];
                if (score < best[i]) { best[i] = score; bidx[i] = c; }
            }
        }
    }

    // cross-thread reduction (64 candidates per vector)
    __syncthreads();
    float* redv = &Es[0][0];
    int*   redi = ((int*)&Es[0][0]) + 1024;
    #pragma unroll
    for (int i = 0; i < 4; i++) {
        int m = vq * 4 + i;
        redv[m * 64 + cq] = best[i];
        redi[m * 64 + cq] = bidx[i];
    }
    __syncthreads();
    if (tid < 16) {
        float bv = redv[tid * 64];
        int bi = redi[tid * 64];
        for (int c2 = 1; c2 < 64; c2++) {
            float v = redv[tid * 64 + c2];
            int ii = redi[tid * 64 + c2];
            if (v < bv || (v == bv && ii < bi)) { bv = v; bi = ii; }
        }
        idx_out[g * NV + bm * 16 + tid] = bi;
    }
}

// ---------------- K4: commitment loss sum ----------------
__global__ __launch_bounds__(256) void k_loss(const float* __restrict__ Y,
                                              const float* __restrict__ ET,
                                              const int* __restrict__ idx,
                                              float* __restrict__ lossAcc) {
    const int total = GG * NV * DD;   // 29,491,200
    const int stride = gridDim.x * 256;
    float s = 0.0f;
    for (int e = blockIdx.x * 256 + threadIdx.x; e < total; e += stride) {
        int g = e / (NV * DD);
        int r = e - g * (NV * DD);
        int v = r >> 9, d = r & 511;
        int ii = idx[g * NV + v];
        float q = ET[(g * KK + ii) * DD + d];
        int b = v / TT, t = v - b * TT;
        int p = g * DD + d;
        int sg = p / FIXD, f = p - sg * FIXD;
        float zv = Y[(b * WW + t * OVL + sg) * FIXD + f];
        float df = q - zv;
        s = fmaf(df, df, s);
    }
    __shared__ float red[256];
    red[threadIdx.x] = s;
    __syncthreads();
    for (int off = 128; off; off >>= 1) {
        if (threadIdx.x < off) red[threadIdx.x] += red[threadIdx.x + off];
        __syncthreads();
    }
    if (threadIdx.x == 0) atomicAdd(lossAcc, red[0]);
}

// ---------------- K5: fused gather + proj_up GEMM + inverse permute ----------------
// out[b,c,h,w] = sum_f zq[n][f] * w_up[dout][f];  n=(b,w), dout=(c,h)
__global__ __launch_bounds__(256) void k_gemm_up(const float* __restrict__ ET,
                                                 const int* __restrict__ idx,
                                                 const float* __restrict__ w_up,
                                                 float* __restrict__ out) {
    __shared__ float As[16][68];
    __shared__ float Bs[16][68];
    __shared__ float Cs[64][68];
    const int bm = blockIdx.x, bn = blockIdx.y;
    const int tid = threadIdx.x;
    const int rbase = (tid >> 4) << 2;
    const int cbase = (tid & 15) << 2;
    const int n0 = bm * 64, dout0 = bn * 64;
    float acc[4][4] = {};
    for (int kt = 0; kt < FIXD; kt += 16) {
        {
            // per-row float4 gather from codebook: row = tid>>2, q = tid&3
            int row = tid >> 2, q = tid & 3;
            int n = n0 + row;
            int b = n / WW, w = n - b * WW;
            int t = w >> 2, s = w & 3;
            int p = s * FIXD + kt;        // 16-f run stays inside one 512-block
            int g = p >> 9, d = p & 511;
            int ii = idx[g * NV + b * TT + t];
            const float4 v = *(const float4*)&ET[((g << 10) + ii) * DD + d + q * 4];
            As[q * 4 + 0][row] = v.x;
            As[q * 4 + 1][row] = v.y;
            As[q * 4 + 2][row] = v.z;
            As[q * 4 + 3][row] = v.w;
        }
        {
            int col = tid >> 2, q = tid & 3;
            const float4 v = *(const float4*)&w_up[(dout0 + col) * FIXD + kt + q * 4];
            Bs[q * 4 + 0][col] = v.x;
            Bs[q * 4 + 1][col] = v.y;
            Bs[q * 4 + 2][col] = v.z;
            Bs[q * 4 + 3][col] = v.w;
        }
        __syncthreads();
        #pragma unroll
        for (int k = 0; k < 16; k++) {
            const float4 a = *(const float4*)&As[k][rbase];
            const float4 b = *(const float4*)&Bs[k][cbase];
            const float av[4] = {a.x, a.y, a.z, a.w};
            const float bv[4] = {b.x, b.y, b.z, b.w};
            #pragma unroll
            for (int i = 0; i < 4; i++)
                #pragma unroll
                for (int j = 0; j < 4; j++)
                    acc[i][j] = fmaf(av[i], bv[j], acc[i][j]);
        }
        __syncthreads();
    }
    // stage C through LDS so global writes are w-coalesced
    #pragma unroll
    for (int i = 0; i < 4; i++) {
        float4 o;
        o.x = acc[i][0]; o.y = acc[i][1]; o.z = acc[i][2]; o.w = acc[i][3];
        *(float4*)&Cs[rbase + i][cbase] = o;
    }
    __syncthreads();
    #pragma unroll
    for (int i = 0; i < 16; i++) {
        int flat = tid + i * 256;       // 0..4095
        int row = flat & 63, col = flat >> 6;
        int n = n0 + row, dout = dout0 + col;
        int b = n / WW, w = n - b * WW;
        int c = dout / HH, h = dout - c * HH;
        out[((b * CC + c) * HH + h) * WW + w] = Cs[row][col];
    }
}

// ---------------- K6: finalize loss scalar ----------------
__global__ void k_finish(const float* __restrict__ lossAcc, float* __restrict__ out) {
    if (threadIdx.x == 0)
        out[58982400] = lossAcc[0] * (0.25f / 29491200.0f);
}

extern "C" void kernel_launch(void* const* d_in, const int* in_sizes, int n_in,
                              void* d_out, int out_size, void* d_ws, size_t ws_size,
                              hipStream_t stream) {
    const float* z      = (const float*)d_in[0];
    const float* w_down = (const float*)d_in[1];
    const float* w_up   = (const float*)d_in[2];
    const float* emb    = (const float*)d_in[3];
    float* out = (float*)d_out;

    float* ws    = (float*)d_ws;
    float* Y     = ws + Y_OFF;
    float* ET    = ws + ET_OFF;
    float* norms = ws + NORM_OFF;
    int*   idx   = (int*)(ws + IDX_OFF);
    float* lossA = ws + LOSS_OFF;

    hipMemsetAsync(lossA, 0, sizeof(float), stream);

    dim3 gdown(600, 12);
    k_gemm_down<<<gdown, 256, 0, stream>>>(z, w_down, Y);

    k_transpose<<<(GG * KK * DD + 255) / 256, 256, 0, stream>>>(emb, ET);
    k_norms<<<GG * KK, 64, 0, stream>>>(ET, norms);

    dim3 gdist(600, GG);
    k_dist<<<gdist, 256, 0, stream>>>(Y, ET, norms, idx);

    k_loss<<<2048, 256, 0, stream>>>(Y, ET, idx, lossA);

    dim3 gup(600, 24);
    k_gemm_up<<<gup, 256, 0, stream>>>(ET, idx, w_up, out);

    k_finish<<<1, 64, 0, stream>>>(lossA, out);
}

// Round 2
// 3303.598 us; speedup vs baseline: 1.2025x; 1.2025x over previous
//
#include <hip/hip_runtime.h>

#define BB 32
#define CC 128
#define HH 12
#define WW 1200
#define DIN 1536
#define FIXD 768
#define OVL 4
#define GG 6
#define DD 512
#define KK 1024
#define TT 300
#define NV 9600        /* B*T vectors per group */
#define MROWS 38400    /* B*W */

// workspace layout (float offsets)
#define Y_OFF     0
#define ET_OFF    29491200
#define NORM_OFF  32636928
#define BEST_OFF  32643072   /* 57600 uint64 = 115200 floats */
#define LOSS_OFF  32758272

// ---------------- K1: fused gather + proj_down GEMM ----------------
// Y[n][f] = sum_k z_perm[n][k] * w_down[f][k];  n=(b,w), k=(c,h)
__global__ __launch_bounds__(256) void k_gemm_down(const float* __restrict__ z,
                                                   const float* __restrict__ w_down,
                                                   float* __restrict__ Y) {
    __shared__ float As[16][68];
    __shared__ float Bs[16][68];
    const int bm = blockIdx.x, bn = blockIdx.y;
    const int tid = threadIdx.x;
    const int rbase = (tid >> 4) << 2;
    const int cbase = (tid & 15) << 2;
    const int n0 = bm * 64, f0 = bn * 64;
    float acc[4][4] = {};
    for (int kt = 0; kt < DIN; kt += 16) {
        #pragma unroll
        for (int i = 0; i < 4; i++) {
            int flat = tid + i * 256;
            int row = flat & 63, kk = flat >> 6;
            int n = n0 + row;
            int k = kt + kk;
            int b = n / WW, w = n - b * WW;
            int c = k / HH, h = k - c * HH;
            As[kk][row] = z[((b * CC + c) * HH + h) * WW + w];
        }
        {
            int col = tid >> 2, q = tid & 3;
            const float4 v = *(const float4*)&w_down[(f0 + col) * DIN + kt + q * 4];
            Bs[q * 4 + 0][col] = v.x;
            Bs[q * 4 + 1][col] = v.y;
            Bs[q * 4 + 2][col] = v.z;
            Bs[q * 4 + 3][col] = v.w;
        }
        __syncthreads();
        #pragma unroll
        for (int k = 0; k < 16; k++) {
            const float4 a = *(const float4*)&As[k][rbase];
            const float4 b = *(const float4*)&Bs[k][cbase];
            const float av[4] = {a.x, a.y, a.z, a.w};
            const float bv[4] = {b.x, b.y, b.z, b.w};
            #pragma unroll
            for (int i = 0; i < 4; i++)
                #pragma unroll
                for (int j = 0; j < 4; j++)
                    acc[i][j] = fmaf(av[i], bv[j], acc[i][j]);
        }
        __syncthreads();
    }
    #pragma unroll
    for (int i = 0; i < 4; i++) {
        float4 o;
        o.x = acc[i][0]; o.y = acc[i][1]; o.z = acc[i][2]; o.w = acc[i][3];
        *(float4*)&Y[(n0 + rbase + i) * FIXD + f0 + cbase] = o;
    }
}

// ---------------- K2: transpose codebook emb(g,d,k) -> ET(g,k,d) ----------------
__global__ __launch_bounds__(256) void k_transpose(const float* __restrict__ emb,
                                                   float* __restrict__ ET) {
    int i = blockIdx.x * 256 + threadIdx.x;
    if (i >= GG * KK * DD) return;
    int d = i & 511;
    int rem = i >> 9;          // g*K + k
    int k = rem & 1023;
    int g = rem >> 10;
    ET[i] = emb[((g * DD + d) << 10) + k];
}

// ---------------- K2b: per-code squared norms (fp64 accumulate) ----------------
__global__ __launch_bounds__(64) void k_norms(const float* __restrict__ ET,
                                              float* __restrict__ norms) {
    const int code = blockIdx.x;   // g*K + k, 6144 total
    const int lane = threadIdx.x;
    const float* row = ET + code * DD;
    double s = 0.0;
    #pragma unroll
    for (int r = 0; r < 8; r++) {
        float v = row[lane + r * 64];
        s += (double)v * (double)v;
    }
    #pragma unroll
    for (int off = 32; off; off >>= 1) s += __shfl_down(s, off);
    if (lane == 0) norms[code] = (float)s;
}

// ---------------- K3: tiled distance GEMM + fused argmin (atomicMin merge) ----
// Block = 64 vectors x 128 codes x full K=512. score = |e|^2 - 2 z.e.
// Cross-block merge via packed (monotone(score)<<32 | code) atomicMin.
__global__ __launch_bounds__(256) void k_dist2(const float* __restrict__ Y,
                                               const float* __restrict__ ET,
                                               const float* __restrict__ norms,
                                               unsigned long long* __restrict__ best) {
    __shared__ float Zs[16][68];
    __shared__ float Es[16][132];
    __shared__ unsigned long long red[64][17];
    const int vt = blockIdx.x;      // 0..149
    const int ct = blockIdx.y;      // 0..7
    const int g  = blockIdx.z;      // 0..5
    const int tid = threadIdx.x;
    const int rgrp = tid >> 4, cgrp = tid & 15;
    const int rbase = rgrp * 4, cbase = cgrp * 8;
    const int v0 = vt * 64, c0 = ct * 128;
    const float* ETg = ET + (size_t)g * KK * DD;

    // Z staging address precompute (one float4 per thread per panel)
    const int zrow = tid >> 2, zq = tid & 3;
    const int vz = v0 + zrow;
    const int bz = vz / TT, tz = vz - bz * TT;

    float acc[4][8] = {};

    for (int kt = 0; kt < DD; kt += 16) {
        const int p0 = g * DD + kt;                 // 16-run never crosses a 768-multiple
        const int s = p0 / FIXD, f0 = p0 - s * FIXD;
        {
            const float4 v = *(const float4*)&Y[(bz * WW + tz * OVL + s) * FIXD + f0 + zq * 4];
            Zs[zq * 4 + 0][zrow] = v.x;
            Zs[zq * 4 + 1][zrow] = v.y;
            Zs[zq * 4 + 2][zrow] = v.z;
            Zs[zq * 4 + 3][zrow] = v.w;
        }
        #pragma unroll
        for (int i = 0; i < 2; i++) {
            int flat = tid + i * 256;               // 0..511
            int code = flat >> 2, q = flat & 3;
            const float4 v = *(const float4*)&ETg[(c0 + code) * DD + kt + q * 4];
            Es[q * 4 + 0][code] = v.x;
            Es[q * 4 + 1][code] = v.y;
            Es[q * 4 + 2][code] = v.z;
            Es[q * 4 + 3][code] = v.w;
        }
        __syncthreads();
        #pragma unroll
        for (int k = 0; k < 16; k++) {
            const float4 z4 = *(const float4*)&Zs[k][rbase];
            const float4 ea = *(const float4*)&Es[k][cbase];
            const float4 eb = *(const float4*)&Es[k][cbase + 4];
            const float zv[4] = {z4.x, z4.y, z4.z, z4.w};
            const float ev[8] = {ea.x, ea.y, ea.z, ea.w, eb.x, eb.y, eb.z, eb.w};
            #pragma unroll
            for (int i = 0; i < 4; i++)
                #pragma unroll
                for (int j = 0; j < 8; j++)
                    acc[i][j] = fmaf(zv[i], ev[j], acc[i][j]);
        }
        __syncthreads();
    }

    // fold norms, pack keys, local best per row
    unsigned long long kbest[4];
    #pragma unroll
    for (int i = 0; i < 4; i++) kbest[i] = ~0ull;
    #pragma unroll
    for (int j = 0; j < 8; j++) {
        const int c = c0 + cbase + j;
        const float nrm = norms[(g << 10) + c];
        #pragma unroll
        for (int i = 0; i < 4; i++) {
            float score = nrm - 2.0f * acc[i][j];
            unsigned u = __float_as_uint(score);
            u = (u & 0x80000000u) ? ~u : (u | 0x80000000u);
            unsigned long long key = ((unsigned long long)u << 32) | (unsigned)c;
            if (key < kbest[i]) kbest[i] = key;
        }
    }
    #pragma unroll
    for (int i = 0; i < 4; i++) red[rbase + i][cgrp] = kbest[i];
    __syncthreads();
    if (tid < 64) {
        unsigned long long b = red[tid][0];
        #pragma unroll
        for (int j = 1; j < 16; j++) {
            unsigned long long v = red[tid][j];
            if (v < b) b = v;
        }
        atomicMin(&best[g * NV + v0 + tid], b);
    }
}

// ---------------- K4: commitment loss sum ----------------
__global__ __launch_bounds__(256) void k_loss(const float* __restrict__ Y,
                                              const float* __restrict__ ET,
                                              const unsigned long long* __restrict__ best,
                                              float* __restrict__ lossAcc) {
    const int total = GG * NV * DD;   // 29,491,200
    const int stride = gridDim.x * 256;
    float s = 0.0f;
    for (int e = blockIdx.x * 256 + threadIdx.x; e < total; e += stride) {
        int g = e / (NV * DD);
        int r = e - g * (NV * DD);
        int v = r >> 9, d = r & 511;
        int ii = (int)(unsigned)best[g * NV + v];
        float q = ET[((size_t)(g * KK + ii)) * DD + d];
        int b = v / TT, t = v - b * TT;
        int p = g * DD + d;
        int sg = p / FIXD, f = p - sg * FIXD;
        float zv = Y[(b * WW + t * OVL + sg) * FIXD + f];
        float df = q - zv;
        s = fmaf(df, df, s);
    }
    __shared__ float red[256];
    red[threadIdx.x] = s;
    __syncthreads();
    for (int off = 128; off; off >>= 1) {
        if (threadIdx.x < off) red[threadIdx.x] += red[threadIdx.x + off];
        __syncthreads();
    }
    if (threadIdx.x == 0) atomicAdd(lossAcc, red[0]);
}

// ---------------- K5: fused gather + proj_up GEMM + inverse permute ----------------
// out[b,c,h,w] = sum_f zq[n][f] * w_up[dout][f];  n=(b,w), dout=(c,h)
__global__ __launch_bounds__(256) void k_gemm_up(const float* __restrict__ ET,
                                                 const unsigned long long* __restrict__ best,
                                                 const float* __restrict__ w_up,
                                                 float* __restrict__ out) {
    __shared__ float As[16][68];
    __shared__ float Bs[16][68];
    __shared__ float Cs[64][68];
    const int bm = blockIdx.x, bn = blockIdx.y;
    const int tid = threadIdx.x;
    const int rbase = (tid >> 4) << 2;
    const int cbase = (tid & 15) << 2;
    const int n0 = bm * 64, dout0 = bn * 64;
    float acc[4][4] = {};
    for (int kt = 0; kt < FIXD; kt += 16) {
        {
            // per-row float4 gather from codebook: row = tid>>2, q = tid&3
            int row = tid >> 2, q = tid & 3;
            int n = n0 + row;
            int b = n / WW, w = n - b * WW;
            int t = w >> 2, s = w & 3;
            int p = s * FIXD + kt;        // 16-f run stays inside one 512-block
            int g = p >> 9, d = p & 511;
            int ii = (int)(unsigned)best[g * NV + b * TT + t];
            const float4 v = *(const float4*)&ET[((size_t)((g << 10) + ii)) * DD + d + q * 4];
            As[q * 4 + 0][row] = v.x;
            As[q * 4 + 1][row] = v.y;
            As[q * 4 + 2][row] = v.z;
            As[q * 4 + 3][row] = v.w;
        }
        {
            int col = tid >> 2, q = tid & 3;
            const float4 v = *(const float4*)&w_up[(dout0 + col) * FIXD + kt + q * 4];
            Bs[q * 4 + 0][col] = v.x;
            Bs[q * 4 + 1][col] = v.y;
            Bs[q * 4 + 2][col] = v.z;
            Bs[q * 4 + 3][col] = v.w;
        }
        __syncthreads();
        #pragma unroll
        for (int k = 0; k < 16; k++) {
            const float4 a = *(const float4*)&As[k][rbase];
            const float4 b = *(const float4*)&Bs[k][cbase];
            const float av[4] = {a.x, a.y, a.z, a.w};
            const float bv[4] = {b.x, b.y, b.z, b.w};
            #pragma unroll
            for (int i = 0; i < 4; i++)
                #pragma unroll
                for (int j = 0; j < 4; j++)
                    acc[i][j] = fmaf(av[i], bv[j], acc[i][j]);
        }
        __syncthreads();
    }
    // stage C through LDS so global writes are w-coalesced
    #pragma unroll
    for (int i = 0; i < 4; i++) {
        float4 o;
        o.x = acc[i][0]; o.y = acc[i][1]; o.z = acc[i][2]; o.w = acc[i][3];
        *(float4*)&Cs[rbase + i][cbase] = o;
    }
    __syncthreads();
    #pragma unroll
    for (int i = 0; i < 16; i++) {
        int flat = tid + i * 256;       // 0..4095
        int row = flat & 63, col = flat >> 6;
        int n = n0 + row, dout = dout0 + col;
        int b = n / WW, w = n - b * WW;
        int c = dout / HH, h = dout - c * HH;
        out[((b * CC + c) * HH + h) * WW + w] = Cs[row][col];
    }
}

// ---------------- K6: finalize loss scalar ----------------
__global__ void k_finish(const float* __restrict__ lossAcc, float* __restrict__ out) {
    if (threadIdx.x == 0)
        out[58982400] = lossAcc[0] * (0.25f / 29491200.0f);
}

extern "C" void kernel_launch(void* const* d_in, const int* in_sizes, int n_in,
                              void* d_out, int out_size, void* d_ws, size_t ws_size,
                              hipStream_t stream) {
    const float* z      = (const float*)d_in[0];
    const float* w_down = (const float*)d_in[1];
    const float* w_up   = (const float*)d_in[2];
    const float* emb    = (const float*)d_in[3];
    float* out = (float*)d_out;

    float* ws    = (float*)d_ws;
    float* Y     = ws + Y_OFF;
    float* ET    = ws + ET_OFF;
    float* norms = ws + NORM_OFF;
    unsigned long long* best = (unsigned long long*)(ws + BEST_OFF);
    float* lossA = ws + LOSS_OFF;

    hipMemsetAsync(best, 0xFF, (size_t)GG * NV * sizeof(unsigned long long), stream);
    hipMemsetAsync(lossA, 0, sizeof(float), stream);

    dim3 gdown(600, 12);
    k_gemm_down<<<gdown, 256, 0, stream>>>(z, w_down, Y);

    k_transpose<<<(GG * KK * DD + 255) / 256, 256, 0, stream>>>(emb, ET);
    k_norms<<<GG * KK, 64, 0, stream>>>(ET, norms);

    dim3 gdist(150, 8, GG);
    k_dist2<<<gdist, 256, 0, stream>>>(Y, ET, norms, best);

    k_loss<<<2048, 256, 0, stream>>>(Y, ET, best, lossA);

    dim3 gup(600, 24);
    k_gemm_up<<<gup, 256, 0, stream>>>(ET, best, w_up, out);

    k_finish<<<1, 64, 0, stream>>>(lossA, out);
}

// Round 3
// 2230.098 us; speedup vs baseline: 1.7813x; 1.4814x over previous
//
#include <hip/hip_runtime.h>

#define BB 32
#define CC 128
#define HH 12
#define WW 1200
#define DIN 1536
#define FIXD 768
#define OVL 4
#define GG 6
#define DD 512
#define KK 1024
#define TT 300
#define NV 9600        /* B*T vectors per group */
#define MROWS 38400    /* B*W */

// workspace layout (float offsets)
#define Y_OFF     0          /* 29,491,200 floats; Tab overlays this after k_loss */
#define ET_OFF    29491200
#define NORM_OFF  32636928
#define BEST_OFF  32643072   /* 57600 uint64 = 115200 floats */
#define LOSS_OFF  32758272

// ---------------- K1: proj_down GEMM (z addressed directly; k=(c,h) flattens) ----
// Y[n][f] = sum_k z[b*1843200 + k*1200 + w] * w_down[f*1536+k];  n = b*1200+w
__global__ __launch_bounds__(256) void k_gemm_down(const float* __restrict__ z,
                                                   const float* __restrict__ w_down,
                                                   float* __restrict__ Y) {
    __shared__ float As[16][68];
    __shared__ float Bs[16][132];
    const int bm = blockIdx.x, bn = blockIdx.y;
    const int tid = threadIdx.x;
    const int n0 = bm * 64, f0 = bn * 128;
    // A staging: fixed row per thread, 4 k-slots
    const int arow = tid & 63;
    const int akk0 = tid >> 6;          // 0..3
    const int nA = n0 + arow;
    const int bA = nA / WW, wA = nA - bA * WW;
    const size_t zbase = (size_t)bA * (CC * HH * WW) + wA;
    const int rbase = (tid >> 4) << 2;  // 0..60
    const int cbase = (tid & 15) << 3;  // 0..120
    float acc[4][8] = {};
    for (int kt = 0; kt < DIN; kt += 16) {
        #pragma unroll
        for (int i = 0; i < 4; i++) {
            int kk = akk0 + i * 4;
            As[kk][arow] = z[zbase + (size_t)(kt + kk) * WW];
        }
        #pragma unroll
        for (int i = 0; i < 2; i++) {
            int fl = tid + i * 256;
            int col = fl >> 2, q = fl & 3;
            const float4 v = *(const float4*)&w_down[(size_t)(f0 + col) * DIN + kt + q * 4];
            Bs[q * 4 + 0][col] = v.x;
            Bs[q * 4 + 1][col] = v.y;
            Bs[q * 4 + 2][col] = v.z;
            Bs[q * 4 + 3][col] = v.w;
        }
        __syncthreads();
        #pragma unroll
        for (int k = 0; k < 16; k++) {
            const float4 a  = *(const float4*)&As[k][rbase];
            const float4 ba = *(const float4*)&Bs[k][cbase];
            const float4 bb = *(const float4*)&Bs[k][cbase + 4];
            const float av[4] = {a.x, a.y, a.z, a.w};
            const float bv[8] = {ba.x, ba.y, ba.z, ba.w, bb.x, bb.y, bb.z, bb.w};
            #pragma unroll
            for (int i = 0; i < 4; i++)
                #pragma unroll
                for (int j = 0; j < 8; j++)
                    acc[i][j] = fmaf(av[i], bv[j], acc[i][j]);
        }
        __syncthreads();
    }
    #pragma unroll
    for (int i = 0; i < 4; i++) {
        float4 o0, o1;
        o0.x = acc[i][0]; o0.y = acc[i][1]; o0.z = acc[i][2]; o0.w = acc[i][3];
        o1.x = acc[i][4]; o1.y = acc[i][5]; o1.z = acc[i][6]; o1.w = acc[i][7];
        float* yr = &Y[(size_t)(n0 + rbase + i) * FIXD + f0 + cbase];
        *(float4*)yr = o0;
        *(float4*)(yr + 4) = o1;
    }
}

// ---------------- K2: transpose codebook emb(g,d,k) -> ET(g,k,d) ----------------
__global__ __launch_bounds__(256) void k_transpose(const float* __restrict__ emb,
                                                   float* __restrict__ ET) {
    int i = blockIdx.x * 256 + threadIdx.x;
    if (i >= GG * KK * DD) return;
    int d = i & 511;
    int rem = i >> 9;          // g*K + k
    int k = rem & 1023;
    int g = rem >> 10;
    ET[i] = emb[((g * DD + d) << 10) + k];
}

// ---------------- K2b: per-code squared norms (fp64 accumulate) ----------------
__global__ __launch_bounds__(64) void k_norms(const float* __restrict__ ET,
                                              float* __restrict__ norms) {
    const int code = blockIdx.x;   // g*K + k, 6144 total
    const int lane = threadIdx.x;
    const float* row = ET + code * DD;
    double s = 0.0;
    #pragma unroll
    for (int r = 0; r < 8; r++) {
        float v = row[lane + r * 64];
        s += (double)v * (double)v;
    }
    #pragma unroll
    for (int off = 32; off; off >>= 1) s += __shfl_down(s, off);
    if (lane == 0) norms[code] = (float)s;
}

// ---------------- K3: tiled distance GEMM + fused argmin (atomicMin merge) ----
__global__ __launch_bounds__(256) void k_dist2(const float* __restrict__ Y,
                                               const float* __restrict__ ET,
                                               const float* __restrict__ norms,
                                               unsigned long long* __restrict__ best) {
    __shared__ float Zs[16][68];
    __shared__ float Es[16][132];
    __shared__ unsigned long long red[64][17];
    const int vt = blockIdx.x;      // 0..149
    const int ct = blockIdx.y;      // 0..7
    const int g  = blockIdx.z;      // 0..5
    const int tid = threadIdx.x;
    const int rgrp = tid >> 4, cgrp = tid & 15;
    const int rbase = rgrp * 4, cbase = cgrp * 8;
    const int v0 = vt * 64, c0 = ct * 128;
    const float* ETg = ET + (size_t)g * KK * DD;

    const int zrow = tid >> 2, zq = tid & 3;
    const int vz = v0 + zrow;
    const int bz = vz / TT, tz = vz - bz * TT;

    float acc[4][8] = {};

    for (int kt = 0; kt < DD; kt += 16) {
        const int p0 = g * DD + kt;
        const int s = p0 / FIXD, f0 = p0 - s * FIXD;
        {
            const float4 v = *(const float4*)&Y[(bz * WW + tz * OVL + s) * FIXD + f0 + zq * 4];
            Zs[zq * 4 + 0][zrow] = v.x;
            Zs[zq * 4 + 1][zrow] = v.y;
            Zs[zq * 4 + 2][zrow] = v.z;
            Zs[zq * 4 + 3][zrow] = v.w;
        }
        #pragma unroll
        for (int i = 0; i < 2; i++) {
            int flat = tid + i * 256;
            int code = flat >> 2, q = flat & 3;
            const float4 v = *(const float4*)&ETg[(c0 + code) * DD + kt + q * 4];
            Es[q * 4 + 0][code] = v.x;
            Es[q * 4 + 1][code] = v.y;
            Es[q * 4 + 2][code] = v.z;
            Es[q * 4 + 3][code] = v.w;
        }
        __syncthreads();
        #pragma unroll
        for (int k = 0; k < 16; k++) {
            const float4 z4 = *(const float4*)&Zs[k][rbase];
            const float4 ea = *(const float4*)&Es[k][cbase];
            const float4 eb = *(const float4*)&Es[k][cbase + 4];
            const float zv[4] = {z4.x, z4.y, z4.z, z4.w};
            const float ev[8] = {ea.x, ea.y, ea.z, ea.w, eb.x, eb.y, eb.z, eb.w};
            #pragma unroll
            for (int i = 0; i < 4; i++)
                #pragma unroll
                for (int j = 0; j < 8; j++)
                    acc[i][j] = fmaf(zv[i], ev[j], acc[i][j]);
        }
        __syncthreads();
    }

    unsigned long long kbest[4];
    #pragma unroll
    for (int i = 0; i < 4; i++) kbest[i] = ~0ull;
    #pragma unroll
    for (int j = 0; j < 8; j++) {
        const int c = c0 + cbase + j;
        const float nrm = norms[(g << 10) + c];
        #pragma unroll
        for (int i = 0; i < 4; i++) {
            float score = nrm - 2.0f * acc[i][j];
            unsigned u = __float_as_uint(score);
            u = (u & 0x80000000u) ? ~u : (u | 0x80000000u);
            unsigned long long key = ((unsigned long long)u << 32) | (unsigned)c;
            if (key < kbest[i]) kbest[i] = key;
        }
    }
    #pragma unroll
    for (int i = 0; i < 4; i++) red[rbase + i][cgrp] = kbest[i];
    __syncthreads();
    if (tid < 64) {
        unsigned long long b = red[tid][0];
        #pragma unroll
        for (int j = 1; j < 16; j++) {
            unsigned long long v = red[tid][j];
            if (v < b) b = v;
        }
        atomicMin(&best[g * NV + v0 + tid], b);
    }
}

// ---------------- K4: commitment loss sum ----------------
__global__ __launch_bounds__(256) void k_loss(const float* __restrict__ Y,
                                              const float* __restrict__ ET,
                                              const unsigned long long* __restrict__ best,
                                              float* __restrict__ lossAcc) {
    const int total = GG * NV * DD;   // 29,491,200
    const int stride = gridDim.x * 256;
    float s = 0.0f;
    for (int e = blockIdx.x * 256 + threadIdx.x; e < total; e += stride) {
        int g = e / (NV * DD);
        int r = e - g * (NV * DD);
        int v = r >> 9, d = r & 511;
        int ii = (int)(unsigned)best[g * NV + v];
        float q = ET[((size_t)(g * KK + ii)) * DD + d];
        int b = v / TT, t = v - b * TT;
        int p = g * DD + d;
        int sg = p / FIXD, f = p - sg * FIXD;
        float zv = Y[(b * WW + t * OVL + sg) * FIXD + f];
        float df = q - zv;
        s = fmaf(df, df, s);
    }
    __shared__ float red[256];
    red[threadIdx.x] = s;
    __syncthreads();
    for (int off = 128; off; off >>= 1) {
        if (threadIdx.x < off) red[threadIdx.x] += red[threadIdx.x + off];
        __syncthreads();
    }
    if (threadIdx.x == 0) atomicAdd(lossAcc, red[0]);
}

// ---------------- K5a: per-(segment,code) up-projection table ----------------
// Segments (g, d0, len, f0): the f-columns of w_up each group's d-range hits,
// split where the w-offset s = p/768 changes (groups 1 and 4 straddle).
__constant__ int SEG_G[8]  = {0, 1, 1, 2, 3, 4, 4, 5};
__constant__ int SEG_D0[8] = {0, 0, 256, 0, 0, 0, 256, 0};
__constant__ int SEG_L[8]  = {512, 256, 256, 512, 512, 256, 256, 512};
__constant__ int SEG_F0[8] = {0, 512, 0, 256, 0, 512, 0, 256};

__global__ __launch_bounds__(256) void k_table(const float* __restrict__ ET,
                                               const float* __restrict__ w_up,
                                               float* __restrict__ Tab) {
    __shared__ float As[16][68];
    __shared__ float Bs[16][132];
    const int bm = blockIdx.x;        // 16 code tiles (64)
    const int bn = blockIdx.y;        // 12 dout tiles (128)
    const int seg = blockIdx.z;       // 8 segments
    const int g = SEG_G[seg], d0 = SEG_D0[seg], len = SEG_L[seg], fb = SEG_F0[seg];
    const int tid = threadIdx.x;
    const int k0 = bm * 64, dout0 = bn * 128;
    const int arow = tid >> 2, aq = tid & 3;
    const int rbase = (tid >> 4) << 2;
    const int cbase = (tid & 15) << 3;
    const float* ETg = ET + (size_t)(g << 10) * DD;
    float acc[4][8] = {};
    for (int kt = 0; kt < len; kt += 16) {
        {
            const float4 v = *(const float4*)&ETg[(size_t)(k0 + arow) * DD + d0 + kt + aq * 4];
            As[aq * 4 + 0][arow] = v.x;
            As[aq * 4 + 1][arow] = v.y;
            As[aq * 4 + 2][arow] = v.z;
            As[aq * 4 + 3][arow] = v.w;
        }
        #pragma unroll
        for (int i = 0; i < 2; i++) {
            int fl = tid + i * 256;
            int col = fl >> 2, q = fl & 3;
            const float4 v = *(const float4*)&w_up[(size_t)(dout0 + col) * FIXD + fb + kt + q * 4];
            Bs[q * 4 + 0][col] = v.x;
            Bs[q * 4 + 1][col] = v.y;
            Bs[q * 4 + 2][col] = v.z;
            Bs[q * 4 + 3][col] = v.w;
        }
        __syncthreads();
        #pragma unroll
        for (int k = 0; k < 16; k++) {
            const float4 a  = *(const float4*)&As[k][rbase];
            const float4 ba = *(const float4*)&Bs[k][cbase];
            const float4 bb = *(const float4*)&Bs[k][cbase + 4];
            const float av[4] = {a.x, a.y, a.z, a.w};
            const float bv[8] = {ba.x, ba.y, ba.z, ba.w, bb.x, bb.y, bb.z, bb.w};
            #pragma unroll
            for (int i = 0; i < 4; i++)
                #pragma unroll
                for (int j = 0; j < 8; j++)
                    acc[i][j] = fmaf(av[i], bv[j], acc[i][j]);
        }
        __syncthreads();
    }
    #pragma unroll
    for (int i = 0; i < 4; i++) {
        float4 o0, o1;
        o0.x = acc[i][0]; o0.y = acc[i][1]; o0.z = acc[i][2]; o0.w = acc[i][3];
        o1.x = acc[i][4]; o1.y = acc[i][5]; o1.z = acc[i][6]; o1.w = acc[i][7];
        float* tr = &Tab[(size_t)((seg << 10) + k0 + rbase + i) * DIN + dout0 + cbase];
        *(float4*)tr = o0;
        *(float4*)(tr + 4) = o1;
    }
}

// ---------------- K5b: gather-add scatter to output ----------------
// out[b, dout, w] (dout=(c,h) flattens) = Tab[2s][idx_gE][dout] + Tab[2s+1][idx_gO][dout]
__global__ __launch_bounds__(256) void k_scatter(const float* __restrict__ Tab,
                                                 const unsigned long long* __restrict__ best,
                                                 float* __restrict__ out) {
    __shared__ float Ls[64][65];
    const int dt = blockIdx.x;        // 24 dout tiles (64)
    const int wt = blockIdx.y;        // 19 w tiles (64)
    const int b  = blockIdx.z;        // 32
    const int dout0 = dt * 64, w0 = wt * 64;
    const int wlim = (WW - w0 < 64) ? (WW - w0) : 64;
    const int tid = threadIdx.x;
    const int wi = tid >> 2, q = tid & 3;

    int se = 0;
    size_t rowE = 0, rowO = 0;
    if (wi < wlim) {
        const int w = w0 + wi;
        const int s = w & 3;
        const int t = w >> 2;
        const int gEt[4] = {0, 1, 3, 4};
        const int gOt[4] = {1, 2, 4, 5};
        int ce = (int)(unsigned)best[gEt[s] * NV + b * TT + t];
        int co = (int)(unsigned)best[gOt[s] * NV + b * TT + t];
        se = s;
        rowE = (size_t)(((2 * s) << 10) + ce) * DIN;
        rowO = (size_t)(((2 * s + 1) << 10) + co) * DIN;
    }
    if (wi < wlim) {
        #pragma unroll
        for (int rep = 0; rep < 4; rep++) {
            const int doff = rep * 16 + q * 4;
            const float4 a = *(const float4*)&Tab[rowE + dout0 + doff];
            const float4 c = *(const float4*)&Tab[rowO + dout0 + doff];
            Ls[wi][doff + 0] = a.x + c.x;
            Ls[wi][doff + 1] = a.y + c.y;
            Ls[wi][doff + 2] = a.z + c.z;
            Ls[wi][doff + 3] = a.w + c.w;
        }
    }
    __syncthreads();
    const size_t obase = (size_t)b * (CC * HH * WW) + (size_t)dout0 * WW + w0;
    #pragma unroll
    for (int i = 0; i < 16; i++) {
        int flat = tid + i * 256;
        int dr = flat >> 6, wj = flat & 63;
        if (wj < wlim) out[obase + (size_t)dr * WW + wj] = Ls[wj][dr];
    }
}

// ---------------- K6: finalize loss scalar ----------------
__global__ void k_finish(const float* __restrict__ lossAcc, float* __restrict__ out) {
    if (threadIdx.x == 0)
        out[58982400] = lossAcc[0] * (0.25f / 29491200.0f);
}

extern "C" void kernel_launch(void* const* d_in, const int* in_sizes, int n_in,
                              void* d_out, int out_size, void* d_ws, size_t ws_size,
                              hipStream_t stream) {
    const float* z      = (const float*)d_in[0];
    const float* w_down = (const float*)d_in[1];
    const float* w_up   = (const float*)d_in[2];
    const float* emb    = (const float*)d_in[3];
    float* out = (float*)d_out;

    float* ws    = (float*)d_ws;
    float* Y     = ws + Y_OFF;
    float* Tab   = ws + Y_OFF;        // overlays Y after k_loss (last Y reader)
    float* ET    = ws + ET_OFF;
    float* norms = ws + NORM_OFF;
    unsigned long long* best = (unsigned long long*)(ws + BEST_OFF);
    float* lossA = ws + LOSS_OFF;

    hipMemsetAsync(best, 0xFF, (size_t)GG * NV * sizeof(unsigned long long), stream);
    hipMemsetAsync(lossA, 0, sizeof(float), stream);

    dim3 gdown(600, 6);
    k_gemm_down<<<gdown, 256, 0, stream>>>(z, w_down, Y);

    k_transpose<<<(GG * KK * DD + 255) / 256, 256, 0, stream>>>(emb, ET);
    k_norms<<<GG * KK, 64, 0, stream>>>(ET, norms);

    dim3 gdist(150, 8, GG);
    k_dist2<<<gdist, 256, 0, stream>>>(Y, ET, norms, best);

    k_loss<<<2048, 256, 0, stream>>>(Y, ET, best, lossA);

    dim3 gtab(16, 12, 8);
    k_table<<<gtab, 256, 0, stream>>>(ET, w_up, Tab);

    dim3 gsc(24, 19, 32);
    k_scatter<<<gsc, 256, 0, stream>>>(Tab, best, out);

    k_finish<<<1, 64, 0, stream>>>(lossA, out);
}

// Round 5
// 2152.452 us; speedup vs baseline: 1.8455x; 1.0361x over previous
//
#include <hip/hip_runtime.h>

#define BB 32
#define CC 128
#define HH 12
#define WW 1200
#define DIN 1536
#define FIXD 768
#define OVL 4
#define GG 6
#define DD 512
#define KK 1024
#define TT 300
#define NV 9600        /* B*T vectors per group */
#define MROWS 38400    /* B*W */

// workspace layout (float offsets)
#define Y_OFF     0          /* 29,491,200 floats; Tab overlays this after k_loss */
#define ET_OFF    29491200
#define NORM_OFF  32636928
#define BEST_OFF  32643072   /* 57600 uint64 = 115200 floats */
#define LOSS_OFF  32758272

// ---------------- K1: proj_down fp32 GEMM, 128x128 tile, 8x8/thread ----------
// Y[n][f] = sum_k z[b*1843200 + k*1200 + w] * w_down[f*1536+k];  n = b*1200+w
// Accumulation is strictly k-sequential per output -> bit-identical to the
// R3 kernel's Y (argmin-critical: do NOT change the fmaf chain order).
__global__ __launch_bounds__(256) void k_gemm_down(const float* __restrict__ z,
                                                   const float* __restrict__ w_down,
                                                   float* __restrict__ Y) {
    __shared__ float As[16][132];
    __shared__ float Bs[16][132];
    const int n0 = blockIdx.x * 128, f0 = blockIdx.y * 128;
    const int tid = threadIdx.x;
    // A staging: row fixed per thread (128 rows), 8 k-slots (k = ak0 + 2*i)
    const int arow = tid & 127;
    const int ak0 = tid >> 7;           // 0..1
    const int nA = n0 + arow;
    const int bA = nA / WW, wA = nA - bA * WW;
    const size_t zbase = (size_t)bA * (CC * HH * WW) + wA;
    // B staging: col = tid>>1 (128 cols), two float4 (q = bq, bq+2)
    const int bcol = tid >> 1, bq = tid & 1;
    // compute thread grid 16x16
    const int trow = tid >> 4, tcol = tid & 15;
    float acc[8][8] = {};
    for (int kt = 0; kt < DIN; kt += 16) {
        #pragma unroll
        for (int i = 0; i < 8; i++) {
            const int kk = ak0 + i * 2;
            As[kk][arow] = z[zbase + (size_t)(kt + kk) * WW];
        }
        #pragma unroll
        for (int i = 0; i < 2; i++) {
            const int q = bq + i * 2;
            const float4 v = *(const float4*)&w_down[(size_t)(f0 + bcol) * DIN + kt + q * 4];
            Bs[q * 4 + 0][bcol] = v.x;
            Bs[q * 4 + 1][bcol] = v.y;
            Bs[q * 4 + 2][bcol] = v.z;
            Bs[q * 4 + 3][bcol] = v.w;
        }
        __syncthreads();
        #pragma unroll
        for (int k = 0; k < 16; k++) {
            float av[8], bv[8];
            *(float4*)&av[0] = *(const float4*)&As[k][trow * 8];
            *(float4*)&av[4] = *(const float4*)&As[k][trow * 8 + 4];
            *(float4*)&bv[0] = *(const float4*)&Bs[k][tcol * 8];
            *(float4*)&bv[4] = *(const float4*)&Bs[k][tcol * 8 + 4];
            #pragma unroll
            for (int i = 0; i < 8; i++)
                #pragma unroll
                for (int j = 0; j < 8; j++)
                    acc[i][j] = fmaf(av[i], bv[j], acc[i][j]);
        }
        __syncthreads();
    }
    #pragma unroll
    for (int i = 0; i < 8; i++) {
        float4 o0, o1;
        o0.x = acc[i][0]; o0.y = acc[i][1]; o0.z = acc[i][2]; o0.w = acc[i][3];
        o1.x = acc[i][4]; o1.y = acc[i][5]; o1.z = acc[i][6]; o1.w = acc[i][7];
        float* yr = &Y[(size_t)(n0 + trow * 8 + i) * FIXD + f0 + tcol * 8];
        *(float4*)yr = o0;
        *(float4*)(yr + 4) = o1;
    }
}

// ---------------- K2: transpose codebook emb(g,d,k) -> ET(g,k,d) ----------------
__global__ __launch_bounds__(256) void k_transpose(const float* __restrict__ emb,
                                                   float* __restrict__ ET) {
    int i = blockIdx.x * 256 + threadIdx.x;
    if (i >= GG * KK * DD) return;
    int d = i & 511;
    int rem = i >> 9;
    int k = rem & 1023;
    int g = rem >> 10;
    ET[i] = emb[((g * DD + d) << 10) + k];
}

// ---------------- K2b: per-code squared norms (fp64 accumulate) ----------------
__global__ __launch_bounds__(64) void k_norms(const float* __restrict__ ET,
                                              float* __restrict__ norms) {
    const int code = blockIdx.x;
    const int lane = threadIdx.x;
    const float* row = ET + code * DD;
    double s = 0.0;
    #pragma unroll
    for (int r = 0; r < 8; r++) {
        float v = row[lane + r * 64];
        s += (double)v * (double)v;
    }
    #pragma unroll
    for (int off = 32; off; off >>= 1) s += __shfl_down(s, off);
    if (lane == 0) norms[code] = (float)s;
}

// ---------------- K3: tiled distance GEMM + fused argmin (atomicMin merge) ----
// Scores are exact-fp32, d-sequential -> bit-identical to R3 (argmin-critical).
__global__ __launch_bounds__(256) void k_dist2(const float* __restrict__ Y,
                                               const float* __restrict__ ET,
                                               const float* __restrict__ norms,
                                               unsigned long long* __restrict__ best) {
    __shared__ float Zs[16][68];
    __shared__ float Es[16][132];
    __shared__ unsigned long long red[64][17];
    const int vt = blockIdx.x;
    const int ct = blockIdx.y;
    const int g  = blockIdx.z;
    const int tid = threadIdx.x;
    const int rgrp = tid >> 4, cgrp = tid & 15;
    const int rbase = rgrp * 4, cbase = cgrp * 8;
    const int v0 = vt * 64, c0 = ct * 128;
    const float* ETg = ET + (size_t)g * KK * DD;

    const int zrow = tid >> 2, zq = tid & 3;
    const int vz = v0 + zrow;
    const int bz = vz / TT, tz = vz - bz * TT;

    float acc[4][8] = {};

    for (int kt = 0; kt < DD; kt += 16) {
        const int p0 = g * DD + kt;
        const int s = p0 / FIXD, f0 = p0 - s * FIXD;
        {
            const float4 v = *(const float4*)&Y[(bz * WW + tz * OVL + s) * FIXD + f0 + zq * 4];
            Zs[zq * 4 + 0][zrow] = v.x;
            Zs[zq * 4 + 1][zrow] = v.y;
            Zs[zq * 4 + 2][zrow] = v.z;
            Zs[zq * 4 + 3][zrow] = v.w;
        }
        #pragma unroll
        for (int i = 0; i < 2; i++) {
            int flat = tid + i * 256;
            int code = flat >> 2, q = flat & 3;
            const float4 v = *(const float4*)&ETg[(c0 + code) * DD + kt + q * 4];
            Es[q * 4 + 0][code] = v.x;
            Es[q * 4 + 1][code] = v.y;
            Es[q * 4 + 2][code] = v.z;
            Es[q * 4 + 3][code] = v.w;
        }
        __syncthreads();
        #pragma unroll
        for (int k = 0; k < 16; k++) {
            const float4 z4 = *(const float4*)&Zs[k][rbase];
            const float4 ea = *(const float4*)&Es[k][cbase];
            const float4 eb = *(const float4*)&Es[k][cbase + 4];
            const float zv[4] = {z4.x, z4.y, z4.z, z4.w};
            const float ev[8] = {ea.x, ea.y, ea.z, ea.w, eb.x, eb.y, eb.z, eb.w};
            #pragma unroll
            for (int i = 0; i < 4; i++)
                #pragma unroll
                for (int j = 0; j < 8; j++)
                    acc[i][j] = fmaf(zv[i], ev[j], acc[i][j]);
        }
        __syncthreads();
    }

    unsigned long long kbest[4];
    #pragma unroll
    for (int i = 0; i < 4; i++) kbest[i] = ~0ull;
    #pragma unroll
    for (int j = 0; j < 8; j++) {
        const int c = c0 + cbase + j;
        const float nrm = norms[(g << 10) + c];
        #pragma unroll
        for (int i = 0; i < 4; i++) {
            float score = nrm - 2.0f * acc[i][j];
            unsigned u = __float_as_uint(score);
            u = (u & 0x80000000u) ? ~u : (u | 0x80000000u);
            unsigned long long key = ((unsigned long long)u << 32) | (unsigned)c;
            if (key < kbest[i]) kbest[i] = key;
        }
    }
    #pragma unroll
    for (int i = 0; i < 4; i++) red[rbase + i][cgrp] = kbest[i];
    __syncthreads();
    if (tid < 64) {
        unsigned long long b = red[tid][0];
        #pragma unroll
        for (int j = 1; j < 16; j++) {
            unsigned long long v = red[tid][j];
            if (v < b) b = v;
        }
        atomicMin(&best[g * NV + v0 + tid], b);
    }
}

// ---------------- K4: commitment loss sum (vectorized) ----------------
__global__ __launch_bounds__(256) void k_loss(const float* __restrict__ Y,
                                              const float* __restrict__ ET,
                                              const unsigned long long* __restrict__ best,
                                              float* __restrict__ lossAcc) {
    const int tid = threadIdx.x;
    const int v = blockIdx.x * 32 + (tid >> 3);     // vector id 0..57599
    const int q = tid & 7;
    const int g = v / NV;
    const int r = v - g * NV;
    const int b = r / TT, t = r - b * TT;
    const int ii = (int)(unsigned)best[v];
    const float* et = &ET[((size_t)((g << 10) + ii)) * DD];
    float s = 0.0f;
    #pragma unroll
    for (int j = 0; j < 16; j++) {
        const int d = j * 32 + q * 4;
        const int p = g * DD + d;
        const int sg = p / FIXD, f = p - sg * FIXD;
        const float4 qv = *(const float4*)&et[d];
        const float4 zv = *(const float4*)&Y[(size_t)(b * WW + t * OVL + sg) * FIXD + f];
        float d0 = qv.x - zv.x, d1 = qv.y - zv.y, d2 = qv.z - zv.z, d3 = qv.w - zv.w;
        s = fmaf(d0, d0, s); s = fmaf(d1, d1, s);
        s = fmaf(d2, d2, s); s = fmaf(d3, d3, s);
    }
    __shared__ float red[256];
    red[tid] = s;
    __syncthreads();
    for (int off = 128; off; off >>= 1) {
        if (tid < off) red[tid] += red[tid + off];
        __syncthreads();
    }
    if (tid == 0) atomicAdd(lossAcc, red[0]);
}

// ---------------- K5a: per-(segment,code) up-projection table ----------------
__constant__ int SEG_G[8]  = {0, 1, 1, 2, 3, 4, 4, 5};
__constant__ int SEG_D0[8] = {0, 0, 256, 0, 0, 0, 256, 0};
__constant__ int SEG_L[8]  = {512, 256, 256, 512, 512, 256, 256, 512};
__constant__ int SEG_F0[8] = {0, 512, 0, 256, 0, 512, 0, 256};

__global__ __launch_bounds__(256) void k_table(const float* __restrict__ ET,
                                               const float* __restrict__ w_up,
                                               float* __restrict__ Tab) {
    __shared__ float As[16][68];
    __shared__ float Bs[16][132];
    const int bm = blockIdx.x;
    const int bn = blockIdx.y;
    const int seg = blockIdx.z;
    const int g = SEG_G[seg], d0 = SEG_D0[seg], len = SEG_L[seg], fb = SEG_F0[seg];
    const int tid = threadIdx.x;
    const int k0 = bm * 64, dout0 = bn * 128;
    const int arow = tid >> 2, aq = tid & 3;
    const int rbase = (tid >> 4) << 2;
    const int cbase = (tid & 15) << 3;
    const float* ETg = ET + (size_t)(g << 10) * DD;
    float acc[4][8] = {};
    for (int kt = 0; kt < len; kt += 16) {
        {
            const float4 v = *(const float4*)&ETg[(size_t)(k0 + arow) * DD + d0 + kt + aq * 4];
            As[aq * 4 + 0][arow] = v.x;
            As[aq * 4 + 1][arow] = v.y;
            As[aq * 4 + 2][arow] = v.z;
            As[aq * 4 + 3][arow] = v.w;
        }
        #pragma unroll
        for (int i = 0; i < 2; i++) {
            int fl = tid + i * 256;
            int col = fl >> 2, q = fl & 3;
            const float4 v = *(const float4*)&w_up[(size_t)(dout0 + col) * FIXD + fb + kt + q * 4];
            Bs[q * 4 + 0][col] = v.x;
            Bs[q * 4 + 1][col] = v.y;
            Bs[q * 4 + 2][col] = v.z;
            Bs[q * 4 + 3][col] = v.w;
        }
        __syncthreads();
        #pragma unroll
        for (int k = 0; k < 16; k++) {
            const float4 a  = *(const float4*)&As[k][rbase];
            const float4 ba = *(const float4*)&Bs[k][cbase];
            const float4 bb = *(const float4*)&Bs[k][cbase + 4];
            const float av[4] = {a.x, a.y, a.z, a.w};
            const float bv[8] = {ba.x, ba.y, ba.z, ba.w, bb.x, bb.y, bb.z, bb.w};
            #pragma unroll
            for (int i = 0; i < 4; i++)
                #pragma unroll
                for (int j = 0; j < 8; j++)
                    acc[i][j] = fmaf(av[i], bv[j], acc[i][j]);
        }
        __syncthreads();
    }
    #pragma unroll
    for (int i = 0; i < 4; i++) {
        float4 o0, o1;
        o0.x = acc[i][0]; o0.y = acc[i][1]; o0.z = acc[i][2]; o0.w = acc[i][3];
        o1.x = acc[i][4]; o1.y = acc[i][5]; o1.z = acc[i][6]; o1.w = acc[i][7];
        float* tr = &Tab[(size_t)((seg << 10) + k0 + rbase + i) * DIN + dout0 + cbase];
        *(float4*)tr = o0;
        *(float4*)(tr + 4) = o1;
    }
}

// ---------------- K5b: gather-add scatter to output ----------------
__global__ __launch_bounds__(256) void k_scatter(const float* __restrict__ Tab,
                                                 const unsigned long long* __restrict__ best,
                                                 float* __restrict__ out) {
    __shared__ float Ls[64][65];
    const int dt = blockIdx.x;
    const int wt = blockIdx.y;
    const int b  = blockIdx.z;
    const int dout0 = dt * 64, w0 = wt * 64;
    const int wlim = (WW - w0 < 64) ? (WW - w0) : 64;
    const int tid = threadIdx.x;
    const int wi = tid >> 2, q = tid & 3;

    if (wi < wlim) {
        const int w = w0 + wi;
        const int s = w & 3;
        const int t = w >> 2;
        const int gEt[4] = {0, 1, 3, 4};
        const int gOt[4] = {1, 2, 4, 5};
        int ce = (int)(unsigned)best[gEt[s] * NV + b * TT + t];
        int co = (int)(unsigned)best[gOt[s] * NV + b * TT + t];
        size_t rowE = (size_t)(((2 * s) << 10) + ce) * DIN;
        size_t rowO = (size_t)(((2 * s + 1) << 10) + co) * DIN;
        #pragma unroll
        for (int rep = 0; rep < 4; rep++) {
            const int doff = rep * 16 + q * 4;
            const float4 a = *(const float4*)&Tab[rowE + dout0 + doff];
            const float4 c = *(const float4*)&Tab[rowO + dout0 + doff];
            Ls[wi][doff + 0] = a.x + c.x;
            Ls[wi][doff + 1] = a.y + c.y;
            Ls[wi][doff + 2] = a.z + c.z;
            Ls[wi][doff + 3] = a.w + c.w;
        }
    }
    __syncthreads();
    const size_t obase = (size_t)b * (CC * HH * WW) + (size_t)dout0 * WW + w0;
    #pragma unroll
    for (int i = 0; i < 16; i++) {
        int flat = tid + i * 256;
        int dr = flat >> 6, wj = flat & 63;
        if (wj < wlim) out[obase + (size_t)dr * WW + wj] = Ls[wj][dr];
    }
}

// ---------------- K6: finalize loss scalar ----------------
__global__ void k_finish(const float* __restrict__ lossAcc, float* __restrict__ out) {
    if (threadIdx.x == 0)
        out[58982400] = lossAcc[0] * (0.25f / 29491200.0f);
}

extern "C" void kernel_launch(void* const* d_in, const int* in_sizes, int n_in,
                              void* d_out, int out_size, void* d_ws, size_t ws_size,
                              hipStream_t stream) {
    const float* z      = (const float*)d_in[0];
    const float* w_down = (const float*)d_in[1];
    const float* w_up   = (const float*)d_in[2];
    const float* emb    = (const float*)d_in[3];
    float* out = (float*)d_out;

    float* ws    = (float*)d_ws;
    float* Y     = ws + Y_OFF;
    float* Tab   = ws + Y_OFF;        // overlays Y after k_loss (last Y reader)
    float* ET    = ws + ET_OFF;
    float* norms = ws + NORM_OFF;
    unsigned long long* best = (unsigned long long*)(ws + BEST_OFF);
    float* lossA = ws + LOSS_OFF;

    hipMemsetAsync(best, 0xFF, (size_t)GG * NV * sizeof(unsigned long long), stream);
    hipMemsetAsync(lossA, 0, sizeof(float), stream);

    dim3 gdown(300, 6);
    k_gemm_down<<<gdown, 256, 0, stream>>>(z, w_down, Y);

    k_transpose<<<(GG * KK * DD + 255) / 256, 256, 0, stream>>>(emb, ET);
    k_norms<<<GG * KK, 64, 0, stream>>>(ET, norms);

    dim3 gdist(150, 8, GG);
    k_dist2<<<gdist, 256, 0, stream>>>(Y, ET, norms, best);

    k_loss<<<1800, 256, 0, stream>>>(Y, ET, best, lossA);

    dim3 gtab(16, 12, 8);
    k_table<<<gtab, 256, 0, stream>>>(ET, w_up, Tab);

    dim3 gsc(24, 19, 32);
    k_scatter<<<gsc, 256, 0, stream>>>(Tab, best, out);

    k_finish<<<1, 64, 0, stream>>>(lossA, out);
}

// Round 6
// 2145.836 us; speedup vs baseline: 1.8512x; 1.0031x over previous
//
#include <hip/hip_runtime.h>

#define BB 32
#define CC 128
#define HH 12
#define WW 1200
#define DIN 1536
#define FIXD 768
#define OVL 4
#define GG 6
#define DD 512
#define KK 1024
#define TT 300
#define NV 9600        /* B*T vectors per group */
#define MROWS 38400    /* B*W */

// workspace layout (float offsets)
#define Y_OFF     0          /* 29,491,200 floats; Tab overlays this after k_loss */
#define ET_OFF    29491200
#define NORM_OFF  32636928
#define BEST_OFF  32643072   /* 57600 uint64 = 115200 floats */
#define LOSS_OFF  32758272

// LDS column swizzle for B-side tiles: chunk starting banks spread to 2-way.
// store: col' = col + 4*(col>>5); read base for 8-float group t: t*8 + 4*(t>>2)
#define BSWZ(c) ((c) + 4 * ((c) >> 5))

// ---------------- K1: proj_down fp32 GEMM, 128x128 tile, 8x8/thread ----------
// Y[n][f] = sum_k z[b*1843200 + k*1200 + w] * w_down[f*1536+k];  n = b*1200+w
// Accumulation is strictly k-sequential per output -> bit-identical to the
// R3/R5 kernels' Y (argmin-critical: do NOT change the fmaf chain order).
__global__ __launch_bounds__(256) void k_gemm_down(const float* __restrict__ z,
                                                   const float* __restrict__ w_down,
                                                   float* __restrict__ Y) {
    __shared__ float As[16][132];
    __shared__ float Bs[16][140];
    const int n0 = blockIdx.x * 128, f0 = blockIdx.y * 128;
    const int tid = threadIdx.x;
    // A staging: row fixed per thread (128 rows), 8 k-slots (k = ak0 + 2*i)
    const int arow = tid & 127;
    const int ak0 = tid >> 7;           // 0..1
    const int nA = n0 + arow;
    const int bA = nA / WW, wA = nA - bA * WW;
    const size_t zbase = (size_t)bA * (CC * HH * WW) + wA;
    // B staging: col = tid>>1 (128 cols), two float4 (q = bq, bq+2)
    const int bcol = tid >> 1, bq = tid & 1;
    const int bsc = BSWZ(bcol);
    // compute thread grid 16x16
    const int trow = tid >> 4, tcol = tid & 15;
    const int bread = tcol * 8 + 4 * (tcol >> 2);   // swizzled read base
    float acc[8][8] = {};
    for (int kt = 0; kt < DIN; kt += 16) {
        #pragma unroll
        for (int i = 0; i < 8; i++) {
            const int kk = ak0 + i * 2;
            As[kk][arow] = z[zbase + (size_t)(kt + kk) * WW];
        }
        #pragma unroll
        for (int i = 0; i < 2; i++) {
            const int q = bq + i * 2;
            const float4 v = *(const float4*)&w_down[(size_t)(f0 + bcol) * DIN + kt + q * 4];
            Bs[q * 4 + 0][bsc] = v.x;
            Bs[q * 4 + 1][bsc] = v.y;
            Bs[q * 4 + 2][bsc] = v.z;
            Bs[q * 4 + 3][bsc] = v.w;
        }
        __syncthreads();
        #pragma unroll
        for (int k = 0; k < 16; k++) {
            float av[8], bv[8];
            *(float4*)&av[0] = *(const float4*)&As[k][trow * 8];
            *(float4*)&av[4] = *(const float4*)&As[k][trow * 8 + 4];
            *(float4*)&bv[0] = *(const float4*)&Bs[k][bread];
            *(float4*)&bv[4] = *(const float4*)&Bs[k][bread + 4];
            #pragma unroll
            for (int i = 0; i < 8; i++)
                #pragma unroll
                for (int j = 0; j < 8; j++)
                    acc[i][j] = fmaf(av[i], bv[j], acc[i][j]);
        }
        __syncthreads();
    }
    #pragma unroll
    for (int i = 0; i < 8; i++) {
        float4 o0, o1;
        o0.x = acc[i][0]; o0.y = acc[i][1]; o0.z = acc[i][2]; o0.w = acc[i][3];
        o1.x = acc[i][4]; o1.y = acc[i][5]; o1.z = acc[i][6]; o1.w = acc[i][7];
        float* yr = &Y[(size_t)(n0 + trow * 8 + i) * FIXD + f0 + tcol * 8];
        *(float4*)yr = o0;
        *(float4*)(yr + 4) = o1;
    }
}

// ---------------- K2: transpose codebook emb(g,d,k) -> ET(g,k,d) ----------------
__global__ __launch_bounds__(256) void k_transpose(const float* __restrict__ emb,
                                                   float* __restrict__ ET) {
    int i = blockIdx.x * 256 + threadIdx.x;
    if (i >= GG * KK * DD) return;
    int d = i & 511;
    int rem = i >> 9;
    int k = rem & 1023;
    int g = rem >> 10;
    ET[i] = emb[((g * DD + d) << 10) + k];
}

// ---------------- K2b: per-code squared norms (fp64 accumulate) ----------------
__global__ __launch_bounds__(64) void k_norms(const float* __restrict__ ET,
                                              float* __restrict__ norms) {
    const int code = blockIdx.x;
    const int lane = threadIdx.x;
    const float* row = ET + code * DD;
    double s = 0.0;
    #pragma unroll
    for (int r = 0; r < 8; r++) {
        float v = row[lane + r * 64];
        s += (double)v * (double)v;
    }
    #pragma unroll
    for (int off = 32; off; off >>= 1) s += __shfl_down(s, off);
    if (lane == 0) norms[code] = (float)s;
}

// ---------------- K3: tiled distance GEMM + fused argmin (atomicMin merge) ----
// Scores are exact-fp32, d-sequential -> bit-identical to R5 (argmin-critical).
__global__ __launch_bounds__(256) void k_dist2(const float* __restrict__ Y,
                                               const float* __restrict__ ET,
                                               const float* __restrict__ norms,
                                               unsigned long long* __restrict__ best) {
    __shared__ float Zs[16][68];
    __shared__ float Es[16][140];
    __shared__ unsigned long long red[64][17];
    const int vt = blockIdx.x;
    const int ct = blockIdx.y;
    const int g  = blockIdx.z;
    const int tid = threadIdx.x;
    const int rgrp = tid >> 4, cgrp = tid & 15;
    const int rbase = rgrp * 4;
    const int eread = cgrp * 8 + 4 * (cgrp >> 2);   // swizzled read base
    const int v0 = vt * 64, c0 = ct * 128;
    const float* ETg = ET + (size_t)g * KK * DD;

    const int zrow = tid >> 2, zq = tid & 3;
    const int vz = v0 + zrow;
    const int bz = vz / TT, tz = vz - bz * TT;

    float acc[4][8] = {};

    for (int kt = 0; kt < DD; kt += 16) {
        const int p0 = g * DD + kt;
        const int s = p0 / FIXD, f0 = p0 - s * FIXD;
        {
            const float4 v = *(const float4*)&Y[(bz * WW + tz * OVL + s) * FIXD + f0 + zq * 4];
            Zs[zq * 4 + 0][zrow] = v.x;
            Zs[zq * 4 + 1][zrow] = v.y;
            Zs[zq * 4 + 2][zrow] = v.z;
            Zs[zq * 4 + 3][zrow] = v.w;
        }
        #pragma unroll
        for (int i = 0; i < 2; i++) {
            int flat = tid + i * 256;
            int code = flat >> 2, q = flat & 3;
            const int sc = BSWZ(code);
            const float4 v = *(const float4*)&ETg[(c0 + code) * DD + kt + q * 4];
            Es[q * 4 + 0][sc] = v.x;
            Es[q * 4 + 1][sc] = v.y;
            Es[q * 4 + 2][sc] = v.z;
            Es[q * 4 + 3][sc] = v.w;
        }
        __syncthreads();
        #pragma unroll
        for (int k = 0; k < 16; k++) {
            const float4 z4 = *(const float4*)&Zs[k][rbase];
            const float4 ea = *(const float4*)&Es[k][eread];
            const float4 eb = *(const float4*)&Es[k][eread + 4];
            const float zv[4] = {z4.x, z4.y, z4.z, z4.w};
            const float ev[8] = {ea.x, ea.y, ea.z, ea.w, eb.x, eb.y, eb.z, eb.w};
            #pragma unroll
            for (int i = 0; i < 4; i++)
                #pragma unroll
                for (int j = 0; j < 8; j++)
                    acc[i][j] = fmaf(zv[i], ev[j], acc[i][j]);
        }
        __syncthreads();
    }

    unsigned long long kbest[4];
    #pragma unroll
    for (int i = 0; i < 4; i++) kbest[i] = ~0ull;
    #pragma unroll
    for (int j = 0; j < 8; j++) {
        const int c = c0 + cgrp * 8 + j;
        const float nrm = norms[(g << 10) + c];
        #pragma unroll
        for (int i = 0; i < 4; i++) {
            float score = nrm - 2.0f * acc[i][j];
            unsigned u = __float_as_uint(score);
            u = (u & 0x80000000u) ? ~u : (u | 0x80000000u);
            unsigned long long key = ((unsigned long long)u << 32) | (unsigned)c;
            if (key < kbest[i]) kbest[i] = key;
        }
    }
    #pragma unroll
    for (int i = 0; i < 4; i++) red[rbase + i][cgrp] = kbest[i];
    __syncthreads();
    if (tid < 64) {
        unsigned long long b = red[tid][0];
        #pragma unroll
        for (int j = 1; j < 16; j++) {
            unsigned long long v = red[tid][j];
            if (v < b) b = v;
        }
        atomicMin(&best[g * NV + v0 + tid], b);
    }
}

// ---------------- K4: commitment loss sum (vectorized) ----------------
__global__ __launch_bounds__(256) void k_loss(const float* __restrict__ Y,
                                              const float* __restrict__ ET,
                                              const unsigned long long* __restrict__ best,
                                              float* __restrict__ lossAcc) {
    const int tid = threadIdx.x;
    const int v = blockIdx.x * 32 + (tid >> 3);     // vector id 0..57599
    const int q = tid & 7;
    const int g = v / NV;
    const int r = v - g * NV;
    const int b = r / TT, t = r - b * TT;
    const int ii = (int)(unsigned)best[v];
    const float* et = &ET[((size_t)((g << 10) + ii)) * DD];
    float s = 0.0f;
    #pragma unroll
    for (int j = 0; j < 16; j++) {
        const int d = j * 32 + q * 4;
        const int p = g * DD + d;
        const int sg = p / FIXD, f = p - sg * FIXD;
        const float4 qv = *(const float4*)&et[d];
        const float4 zv = *(const float4*)&Y[(size_t)(b * WW + t * OVL + sg) * FIXD + f];
        float d0 = qv.x - zv.x, d1 = qv.y - zv.y, d2 = qv.z - zv.z, d3 = qv.w - zv.w;
        s = fmaf(d0, d0, s); s = fmaf(d1, d1, s);
        s = fmaf(d2, d2, s); s = fmaf(d3, d3, s);
    }
    __shared__ float red[256];
    red[tid] = s;
    __syncthreads();
    for (int off = 128; off; off >>= 1) {
        if (tid < off) red[tid] += red[tid + off];
        __syncthreads();
    }
    if (tid == 0) atomicAdd(lossAcc, red[0]);
}

// ---------------- K5a: per-(segment,code) up-projection table ----------------
__constant__ int SEG_G[8]  = {0, 1, 1, 2, 3, 4, 4, 5};
__constant__ int SEG_D0[8] = {0, 0, 256, 0, 0, 0, 256, 0};
__constant__ int SEG_L[8]  = {512, 256, 256, 512, 512, 256, 256, 512};
__constant__ int SEG_F0[8] = {0, 512, 0, 256, 0, 512, 0, 256};

__global__ __launch_bounds__(256) void k_table(const float* __restrict__ ET,
                                               const float* __restrict__ w_up,
                                               float* __restrict__ Tab) {
    __shared__ float As[16][68];
    __shared__ float Bs[16][140];
    const int bm = blockIdx.x;
    const int bn = blockIdx.y;
    const int seg = blockIdx.z;
    const int g = SEG_G[seg], d0 = SEG_D0[seg], len = SEG_L[seg], fb = SEG_F0[seg];
    const int tid = threadIdx.x;
    const int k0 = bm * 64, dout0 = bn * 128;
    const int arow = tid >> 2, aq = tid & 3;
    const int rbase = (tid >> 4) << 2;
    const int cgrp = tid & 15;
    const int bread = cgrp * 8 + 4 * (cgrp >> 2);
    const float* ETg = ET + (size_t)(g << 10) * DD;
    float acc[4][8] = {};
    for (int kt = 0; kt < len; kt += 16) {
        {
            const float4 v = *(const float4*)&ETg[(size_t)(k0 + arow) * DD + d0 + kt + aq * 4];
            As[aq * 4 + 0][arow] = v.x;
            As[aq * 4 + 1][arow] = v.y;
            As[aq * 4 + 2][arow] = v.z;
            As[aq * 4 + 3][arow] = v.w;
        }
        #pragma unroll
        for (int i = 0; i < 2; i++) {
            int fl = tid + i * 256;
            int col = fl >> 2, q = fl & 3;
            const int sc = BSWZ(col);
            const float4 v = *(const float4*)&w_up[(size_t)(dout0 + col) * FIXD + fb + kt + q * 4];
            Bs[q * 4 + 0][sc] = v.x;
            Bs[q * 4 + 1][sc] = v.y;
            Bs[q * 4 + 2][sc] = v.z;
            Bs[q * 4 + 3][sc] = v.w;
        }
        __syncthreads();
        #pragma unroll
        for (int k = 0; k < 16; k++) {
            const float4 a  = *(const float4*)&As[k][rbase];
            const float4 ba = *(const float4*)&Bs[k][bread];
            const float4 bb = *(const float4*)&Bs[k][bread + 4];
            const float av[4] = {a.x, a.y, a.z, a.w};
            const float bv[8] = {ba.x, ba.y, ba.z, ba.w, bb.x, bb.y, bb.z, bb.w};
            #pragma unroll
            for (int i = 0; i < 4; i++)
                #pragma unroll
                for (int j = 0; j < 8; j++)
                    acc[i][j] = fmaf(av[i], bv[j], acc[i][j]);
        }
        __syncthreads();
    }
    #pragma unroll
    for (int i = 0; i < 4; i++) {
        float4 o0, o1;
        o0.x = acc[i][0]; o0.y = acc[i][1]; o0.z = acc[i][2]; o0.w = acc[i][3];
        o1.x = acc[i][4]; o1.y = acc[i][5]; o1.z = acc[i][6]; o1.w = acc[i][7];
        float* tr = &Tab[(size_t)((seg << 10) + k0 + rbase + i) * DIN + dout0 + cgrp * 8];
        *(float4*)tr = o0;
        *(float4*)(tr + 4) = o1;
    }
}

// ---------------- K5b: gather-add scatter to output ----------------
__global__ __launch_bounds__(256) void k_scatter(const float* __restrict__ Tab,
                                                 const unsigned long long* __restrict__ best,
                                                 float* __restrict__ out) {
    __shared__ float Ls[64][65];
    const int dt = blockIdx.x;
    const int wt = blockIdx.y;
    const int b  = blockIdx.z;
    const int dout0 = dt * 64, w0 = wt * 64;
    const int wlim = (WW - w0 < 64) ? (WW - w0) : 64;
    const int tid = threadIdx.x;
    const int wi = tid >> 2, q = tid & 3;

    if (wi < wlim) {
        const int w = w0 + wi;
        const int s = w & 3;
        const int t = w >> 2;
        const int gEt[4] = {0, 1, 3, 4};
        const int gOt[4] = {1, 2, 4, 5};
        int ce = (int)(unsigned)best[gEt[s] * NV + b * TT + t];
        int co = (int)(unsigned)best[gOt[s] * NV + b * TT + t];
        size_t rowE = (size_t)(((2 * s) << 10) + ce) * DIN;
        size_t rowO = (size_t)(((2 * s + 1) << 10) + co) * DIN;
        #pragma unroll
        for (int rep = 0; rep < 4; rep++) {
            const int doff = rep * 16 + q * 4;
            const float4 a = *(const float4*)&Tab[rowE + dout0 + doff];
            const float4 c = *(const float4*)&Tab[rowO + dout0 + doff];
            Ls[wi][doff + 0] = a.x + c.x;
            Ls[wi][doff + 1] = a.y + c.y;
            Ls[wi][doff + 2] = a.z + c.z;
            Ls[wi][doff + 3] = a.w + c.w;
        }
    }
    __syncthreads();
    const size_t obase = (size_t)b * (CC * HH * WW) + (size_t)dout0 * WW + w0;
    #pragma unroll
    for (int i = 0; i < 16; i++) {
        int flat = tid + i * 256;
        int dr = flat >> 6, wj = flat & 63;
        if (wj < wlim) out[obase + (size_t)dr * WW + wj] = Ls[wj][dr];
    }
}

// ---------------- K6: finalize loss scalar ----------------
__global__ void k_finish(const float* __restrict__ lossAcc, float* __restrict__ out) {
    if (threadIdx.x == 0)
        out[58982400] = lossAcc[0] * (0.25f / 29491200.0f);
}

extern "C" void kernel_launch(void* const* d_in, const int* in_sizes, int n_in,
                              void* d_out, int out_size, void* d_ws, size_t ws_size,
                              hipStream_t stream) {
    const float* z      = (const float*)d_in[0];
    const float* w_down = (const float*)d_in[1];
    const float* w_up   = (const float*)d_in[2];
    const float* emb    = (const float*)d_in[3];
    float* out = (float*)d_out;

    float* ws    = (float*)d_ws;
    float* Y     = ws + Y_OFF;
    float* Tab   = ws + Y_OFF;        // overlays Y after k_loss (last Y reader)
    float* ET    = ws + ET_OFF;
    float* norms = ws + NORM_OFF;
    unsigned long long* best = (unsigned long long*)(ws + BEST_OFF);
    float* lossA = ws + LOSS_OFF;

    hipMemsetAsync(best, 0xFF, (size_t)GG * NV * sizeof(unsigned long long), stream);
    hipMemsetAsync(lossA, 0, sizeof(float), stream);

    dim3 gdown(300, 6);
    k_gemm_down<<<gdown, 256, 0, stream>>>(z, w_down, Y);

    k_transpose<<<(GG * KK * DD + 255) / 256, 256, 0, stream>>>(emb, ET);
    k_norms<<<GG * KK, 64, 0, stream>>>(ET, norms);

    dim3 gdist(150, 8, GG);
    k_dist2<<<gdist, 256, 0, stream>>>(Y, ET, norms, best);

    k_loss<<<1800, 256, 0, stream>>>(Y, ET, best, lossA);

    dim3 gtab(16, 12, 8);
    k_table<<<gtab, 256, 0, stream>>>(ET, w_up, Tab);

    dim3 gsc(24, 19, 32);
    k_scatter<<<gsc, 256, 0, stream>>>(Tab, best, out);

    k_finish<<<1, 64, 0, stream>>>(lossA, out);
}